// Round 8
// baseline (295.855 us; speedup 1.0000x reference)
//
#include <hip/hip_runtime.h>
#include <stdint.h>

#define NN 30000
#define NE 480000
#define NGB 118             // ceil(NN/256) node-groups

// ------------------------- compile-time Clebsch-Gordan -------------------------
constexpr double cfact(int n){ double r=1.0; for(int i=2;i<=n;i++) r*=(double)i; return r; }
constexpr double csqrt_(double x){ if(x<=0.0) return 0.0; double g = x<1.0?1.0:x; for(int i=0;i<200;i++) g = 0.5*(g + x/g); return g; }
constexpr double cg_coeff(int j1,int m1,int j2,int m2,int j,int m){
  if(m != m1+m2) return 0.0;
  int dj = j1-j2; if(dj<0) dj=-dj;
  if(j < dj || j > j1+j2) return 0.0;
  double pre = csqrt_((2*j+1)*cfact(j+j1-j2)*cfact(j-j1+j2)*cfact(j1+j2-j)/cfact(j1+j2+j+1));
  pre = pre * csqrt_(cfact(j+m)*cfact(j-m)*cfact(j1-m1)*cfact(j1+m1)*cfact(j2-m2)*cfact(j2+m2));
  double s = 0.0;
  for(int k=0;k<=j1+j2-j;k++){
    int d0=k, d1=j1+j2-j-k, d2=j1-m1-k, d3=j2+m2-k, d4=j-j2+m1+k, d5=j-j1-m2+k;
    if(d0<0||d1<0||d2<0||d3<0||d4<0||d5<0) continue;
    double term = 1.0/(cfact(d0)*cfact(d1)*cfact(d2)*cfact(d3)*cfact(d4)*cfact(d5));
    s += (k&1) ? -term : term;
  }
  return pre*s;
}

template<int L1,int L2,int LO> struct CGTab { float v[2*LO+1][2*L1+1][2*L2+1]; };

template<int L1,int L2,int LO>
constexpr CGTab<L1,L2,LO> make_cg(){
  CGTab<L1,L2,LO> t{};
  for(int m=-LO;m<=LO;m++)
    for(int p=-L1;p<=L1;p++)
      for(int q=-L2;q<=L2;q++)
        t.v[m+LO][p+L1][q+L2] = (float)cg_coeff(L1,p,L2,q,LO,m);
  return t;
}
template<int L1,int L2,int LO>
constexpr CGTab<L1,L2,LO> CG_TAB = make_cg<L1,L2,LO>();

// T[m] = sum_{p,q} C[m,p,q] av[p] bv[q]
template<int L1,int L2,int LO>
__device__ __forceinline__ void build_T(const float* av, const float* bv, float* T){
  constexpr int MA=2*L1+1, MB=2*L2+1, MO=2*LO+1;
  #pragma unroll
  for(int m=0;m<MO;m++) T[m]=0.f;
  #pragma unroll
  for(int m=0;m<MO;m++)
    #pragma unroll
    for(int p=0;p<MA;p++)
      #pragma unroll
      for(int q=0;q<MB;q++){
        const float cg = CG_TAB<L1,L2,LO>.v[m][p][q];
        if(cg!=0.0f) T[m]=fmaf(cg*av[p],bv[q],T[m]);
      }
}

// ------------------------- rectangular chunk (asymmetric products: yx) -------------------------
template<int L1,int L2,int LO,int CA,int CB>
__device__ __forceinline__ void do_chunk(const float* __restrict__ A,
                                         const float* __restrict__ B,
                                         const float* __restrict__ W, int wb,
                                         float acc[8][2*LO+1])
{
  constexpr int MA=2*L1+1, MB=2*L2+1, MO=2*LO+1;
  float bv[CB][MB];
  #pragma unroll
  for(int d=0;d<CB;d++)
    #pragma unroll
    for(int q=0;q<MB;q++) bv[d][q] = B[(d*MB+q)*NN];
  #pragma unroll 1
  for(int c=0;c<CA;c++){
    float av[MA];
    #pragma unroll
    for(int p=0;p<MA;p++) av[p] = A[(c*MA+p)*NN];
    #pragma unroll
    for(int d=0;d<CB;d++){
      float T[MO];
      build_T<L1,L2,LO>(av, bv[d], T);
      const float* wr = W + (wb + c*CB + d)*8;     // wave-uniform -> s_load
      #pragma unroll
      for(int o=0;o<8;o++){
        float w = wr[o];
        #pragma unroll
        for(int m=0;m<MO;m++) acc[o][m] = fmaf(w, T[m], acc[o][m]);
      }
    }
  }
}

// ---------------- symmetric-product helpers (a==b tensor) ----------------
template<int L1,int L2,int LO,int C,int SGN>
__device__ __forceinline__ void do_chunk_fold(const float* __restrict__ A1,
    const float* __restrict__ A2, const float* __restrict__ W, int wb1, int wb2,
    float acc[8][2*LO+1])
{
  constexpr int MA=2*L1+1, MB=2*L2+1, MO=2*LO+1;
  float bv[C][MB];
  #pragma unroll
  for(int d=0;d<C;d++)
    #pragma unroll
    for(int q=0;q<MB;q++) bv[d][q] = A2[(d*MB+q)*NN];
  #pragma unroll 1
  for(int c=0;c<C;c++){
    float av[MA];
    #pragma unroll
    for(int p=0;p<MA;p++) av[p] = A1[(c*MA+p)*NN];
    #pragma unroll
    for(int d=0;d<C;d++){
      float T[MO];
      build_T<L1,L2,LO>(av, bv[d], T);
      const float* w1 = W + (wb1 + c*C + d)*8;
      const float* w2 = W + (wb2 + d*C + c)*8;
      #pragma unroll
      for(int o=0;o<8;o++){
        float wf = (SGN>0) ? (w1[o] + w2[o]) : (w1[o] - w2[o]);
        #pragma unroll
        for(int m=0;m<MO;m++) acc[o][m] = fmaf(wf, T[m], acc[o][m]);
      }
    }
  }
}

template<int L,int LO,int C,int SGN>
__device__ __forceinline__ void do_chunk_tri(const float* __restrict__ Al,
    const float* __restrict__ W, int wb, float acc[8][2*LO+1])
{
  constexpr int M=2*L+1, MO=2*LO+1;
  float bv[C][M];
  #pragma unroll
  for(int d=0;d<C;d++)
    #pragma unroll
    for(int q=0;q<M;q++) bv[d][q] = Al[(d*M+q)*NN];
  #pragma unroll 1
  for(int c=0;c<C-1;c++){
    float av[M];
    #pragma unroll
    for(int p=0;p<M;p++) av[p] = Al[(c*M+p)*NN];
    #pragma unroll
    for(int d=0;d<C;d++){
      if(d > c){                                  // uniform (scalar) guard
        float T[MO];
        build_T<L,L,LO>(av, bv[d], T);
        const float* w1 = W + (wb + c*C + d)*8;
        const float* w2 = W + (wb + d*C + c)*8;
        #pragma unroll
        for(int o=0;o<8;o++){
          float wf = (SGN>0) ? (w1[o] + w2[o]) : (w1[o] - w2[o]);
          #pragma unroll
          for(int m=0;m<MO;m++) acc[o][m] = fmaf(wf, T[m], acc[o][m]);
        }
      }
    }
  }
}

template<int L,int LO,int C>
__device__ __forceinline__ void do_chunk_diagO(const float* __restrict__ Al,
    const float* __restrict__ W, int wb, float acc[8][2*LO+1])
{
  constexpr int M=2*L+1, MO=2*LO+1;
  #pragma unroll 1
  for(int c=0;c<C;c++){
    float av[M];
    #pragma unroll
    for(int p=0;p<M;p++) av[p] = Al[(c*M+p)*NN];
    float T[MO];
    build_T<L,L,LO>(av, av, T);
    const float* wr = W + (wb + c*C + c)*8;
    #pragma unroll
    for(int o=0;o<8;o++){
      float w = wr[o];
      #pragma unroll
      for(int m=0;m<MO;m++) acc[o][m] = fmaf(w, T[m], acc[o][m]);
    }
  }
}

// ------------------- run chunks: asymmetric (yx) -------------------
template<int LO,int CA,int CB>
__device__ __forceinline__ void run_chunks(
    const float* a0,const float* a1,const float* a2,
    const float* b0,const float* b1,const float* b2,
    const float* __restrict__ W, float acc[8][2*LO+1])
{
  constexpr int S = CA*CB;
  if constexpr (LO==0){
    do_chunk<0,0,0,CA,CB>(a0,b0,W,0*S,acc);
    do_chunk<1,1,0,CA,CB>(a1,b1,W,1*S,acc);
    do_chunk<2,2,0,CA,CB>(a2,b2,W,2*S,acc);
  } else if constexpr (LO==1){
    do_chunk<0,1,1,CA,CB>(a0,b1,W,0*S,acc);
    do_chunk<1,0,1,CA,CB>(a1,b0,W,1*S,acc);
    do_chunk<1,1,1,CA,CB>(a1,b1,W,2*S,acc);
    do_chunk<1,2,1,CA,CB>(a1,b2,W,3*S,acc);
    do_chunk<2,1,1,CA,CB>(a2,b1,W,4*S,acc);
    do_chunk<2,2,1,CA,CB>(a2,b2,W,5*S,acc);
  } else {
    do_chunk<0,2,2,CA,CB>(a0,b2,W,0*S,acc);
    do_chunk<1,1,2,CA,CB>(a1,b1,W,1*S,acc);
    do_chunk<1,2,2,CA,CB>(a1,b2,W,2*S,acc);
    do_chunk<2,0,2,CA,CB>(a2,b0,W,3*S,acc);
    do_chunk<2,1,2,CA,CB>(a2,b1,W,4*S,acc);
    do_chunk<2,2,2,CA,CB>(a2,b2,W,5*S,acc);
  }
}

// ------------------- run chunks: symmetric (yy, xx) with CG-symmetry folding -------------------
template<int LO,int C>
__device__ __forceinline__ void run_chunks_sym(
    const float* a0,const float* a1,const float* a2,
    const float* __restrict__ W, float acc[8][2*LO+1])
{
  constexpr int S = C*C;
  if constexpr (LO==0){
    do_chunk_tri<0,0,C,+1>(a0,W,0*S,acc);  do_chunk_diagO<0,0,C>(a0,W,0*S,acc);
    do_chunk_tri<1,0,C,+1>(a1,W,1*S,acc);  do_chunk_diagO<1,0,C>(a1,W,1*S,acc);
    do_chunk_tri<2,0,C,+1>(a2,W,2*S,acc);  do_chunk_diagO<2,0,C>(a2,W,2*S,acc);
  } else if constexpr (LO==1){
    do_chunk_fold<0,1,1,C,+1>(a0,a1,W,0*S,1*S,acc);
    do_chunk_tri <1,1,C,-1>(a1,W,2*S,acc);
    do_chunk_fold<1,2,1,C,+1>(a1,a2,W,3*S,4*S,acc);
    do_chunk_tri <2,1,C,-1>(a2,W,5*S,acc);
  } else {
    do_chunk_fold<0,2,2,C,+1>(a0,a2,W,0*S,3*S,acc);
    do_chunk_tri <1,2,C,+1>(a1,W,1*S,acc);  do_chunk_diagO<1,2,C>(a1,W,1*S,acc);
    do_chunk_fold<1,2,2,C,-1>(a1,a2,W,2*S,4*S,acc);
    do_chunk_tri <2,2,C,+1>(a2,W,5*S,acc);  do_chunk_diagO<2,2,C>(a2,W,5*S,acc);
  }
}

// One thread = one (node, PROD, LO). y and xs are SoA (row*NN + node).
template<int PROD,int LO>
__device__ __forceinline__ void do_item(int node,
    const float* __restrict__ xs, const float* __restrict__ y,
    const float* __restrict__ W, float* __restrict__ p)
{
  const float *y0 = y  + node, *y1 = y  + 8*NN + node, *y2 = y  + 32*NN + node;
  const float *x0 = xs + node, *x1 = xs + 4*NN + node, *x2 = xs + 16*NN + node;

  float acc[8][2*LO+1];
  #pragma unroll
  for(int o=0;o<8;o++)
    #pragma unroll
    for(int m=0;m<2*LO+1;m++) acc[o][m]=0.f;

  if constexpr (PROD==0)      run_chunks_sym<LO,8>(y0,y1,y2,W,acc);
  else if constexpr (PROD==2) run_chunks_sym<LO,4>(x0,x1,x2,W,acc);
  else                        run_chunks<LO,8,4>(y0,y1,y2,x0,x1,x2,W,acc);

  constexpr int OB = (LO==0)?0:((LO==1)?8:32);
  float* op = p + OB*NN + node;
  #pragma unroll
  for(int o=0;o<8;o++)
    #pragma unroll
    for(int m=0;m<2*LO+1;m++) op[(o*(2*LO+1)+m)*NN] = acc[o][m];
}

struct WPtrs {
  const float* xx[3];
  const float* yx[3];
  const float* yy[3];
};

// XCD-aware flat grid: blocks arranged in super-groups of 72 = 8 node-groups x 9 items.
// Within a super-group, physical block p -> XCD p%8; all 9 items of node-group g share
// p%8 == g%8, so they execute on ONE XCD and reuse its L2 copy of the g-slice of y/xs.
__global__ __launch_bounds__(256) void cg_kernel(
    const float* __restrict__ xs, const float* __restrict__ y, WPtrs w,
    float* __restrict__ p0, float* __restrict__ p1, float* __restrict__ p2)
{
  int p = blockIdx.x;
  int s = p / 72;
  int local = p - s*72;
  int g, item;
  if(s < 14){ g = s*8 + (local & 7);  item = local >> 3; }
  else      { g = 112 + local % 6;    item = local / 6;  }   // tail: 6 groups x 9 items
  int node = g*256 + threadIdx.x;
  if(node >= NN) return;
  switch(item){     // heaviest first (post-fold weights)
    case 0: do_item<1,2>(node,xs,y,w.yx[2],p1); break;
    case 1: do_item<0,2>(node,xs,y,w.yy[2],p0); break;
    case 2: do_item<0,1>(node,xs,y,w.yy[1],p0); break;
    case 3: do_item<1,1>(node,xs,y,w.yx[1],p1); break;
    case 4: do_item<2,2>(node,xs,y,w.xx[2],p2); break;
    case 5: do_item<2,1>(node,xs,y,w.xx[1],p2); break;
    case 6: do_item<0,0>(node,xs,y,w.yy[0],p0); break;
    case 7: do_item<1,0>(node,xs,y,w.yx[0],p1); break;
    case 8: do_item<2,0>(node,xs,y,w.xx[0],p2); break;
  }
}

// ------------------------- sum partials (SoA) -> out (AoS, reference layout) ------------
__global__ __launch_bounds__(256) void sum_kernel(const float* __restrict__ p0,
  const float* __restrict__ p1, const float* __restrict__ p2, float* __restrict__ out)
{
  int i = blockIdx.x*256 + threadIdx.x;
  if(i >= NN*72) return;
  int row, node;
  if(i < NN*8)       { node = i>>3;          row = i&7; }
  else if(i < NN*32) { int r=i-NN*8;  node=r/24; row = 8  + (r - node*24); }
  else               { int r=i-NN*32; node=r/40; row = 32 + (r - node*40); }
  int pi = row*NN + node;
  out[i] = p0[pi] + p1[pi] + p2[pi];
}

// ------------------------- CSR build -------------------------
__global__ __launch_bounds__(256) void hist_kernel(const int* __restrict__ idx, int* __restrict__ cnt)
{
  int e = blockIdx.x*256 + threadIdx.x;
  if(e >= NE) return;
  atomicAdd(&cnt[idx[NE + e]], 1);
}

__global__ __launch_bounds__(256) void scan1_kernel(const int* __restrict__ cnt,
    int* __restrict__ offs, int* __restrict__ bt)
{
  __shared__ int wsum[4], wexc[4];
  int b = blockIdx.x, tid = threadIdx.x;
  int lane = tid & 63, wid = tid >> 6;
  int i0 = b*512 + tid*2;
  int v0 = (i0   < NN) ? cnt[i0]   : 0;
  int v1 = (i0+1 < NN) ? cnt[i0+1] : 0;
  int v = v0+v1, s = v;
  #pragma unroll
  for(int o=1;o<64;o<<=1){ int t=__shfl_up(s,o,64); if(lane>=o) s+=t; }
  if(lane==63) wsum[wid]=s;
  __syncthreads();
  if(tid<4){
    int wv=wsum[tid], x=wv;
    #pragma unroll
    for(int o=1;o<4;o<<=1){ int t=__shfl_up(x,o,4); if(tid>=o) x+=t; }
    wexc[tid]=x-wv;
    if(tid==3) bt[b]=x;
  }
  __syncthreads();
  int excl = s - v + wexc[wid];
  if(i0   < NN) offs[i0]   = excl;
  if(i0+1 < NN) offs[i0+1] = excl + v0;
}

__global__ __launch_bounds__(64) void scan2_kernel(int* __restrict__ bt,
    int* __restrict__ bte, int* __restrict__ offs)
{
  int tid = threadIdx.x;
  int v = bt[tid], s = v;
  #pragma unroll
  for(int o=1;o<64;o<<=1){ int t=__shfl_up(s,o,64); if(tid>=o) s+=t; }
  bte[tid] = s - v;
  if(tid==63) offs[NN] = s;
}

__global__ __launch_bounds__(512) void scan3_kernel(int* __restrict__ offs,
    const int* __restrict__ bte, int* __restrict__ cur)
{
  int i = blockIdx.x*512 + threadIdx.x;
  if(i >= NN) return;
  int o = offs[i] + bte[blockIdx.x];
  offs[i] = o;
  cur[i]  = o;
}

__global__ __launch_bounds__(256) void scatter_kernel(const int* __restrict__ idx,
    const float* __restrict__ ev, int* __restrict__ cur, float4* __restrict__ edges)
{
  int e = blockIdx.x*256 + threadIdx.x;
  if(e >= NE) return;
  int dst = idx[NE + e];
  int pos = atomicAdd(&cur[dst], 1);
  float4 r;
  r.x = __int_as_float(idx[e]);
  r.y = ev[2*e];
  r.z = ev[2*e+1];
  r.w = 0.f;
  edges[pos] = r;
}

// ------------------------- x AoS -> SoA transpose -------------------------
__global__ __launch_bounds__(256) void xpose_kernel(
    const float* __restrict__ x0, const float* __restrict__ x1, const float* __restrict__ x2,
    float* __restrict__ xs)
{
  int t = blockIdx.x*256 + threadIdx.x;    // t = row*NN + node
  if(t >= NN*36) return;
  int row = t / NN, node = t - row*NN;
  float v;
  if(row < 4)       v = x0[node*4  + row];
  else if(row < 16) v = x1[node*12 + (row-4)];
  else              v = x2[node*20 + (row-16)];
  xs[t] = v;
}

// ------------------------- gather: one thread per (node, c); both ech channels ---------
// Halves edge-record reads and scattered x loads vs 8-threads/node.
__global__ __launch_bounds__(256) void gather_kernel(
    const float* __restrict__ x0, const float* __restrict__ x1, const float* __restrict__ x2,
    const float4* __restrict__ edges, const int* __restrict__ offs,
    float* __restrict__ y)
{
  int t = blockIdx.x*256 + threadIdx.x;
  if(t >= NN*4) return;
  int node = t >> 2, c = t & 3;
  float a0[2]={0.f,0.f};
  float a1[2][3]={}, a2[2][5]={};
  int k0 = offs[node], k1 = offs[node+1];
  for(int k=k0;k<k1;k++){
    float4 ed = edges[k];
    int src = __float_as_int(ed.x);
    float e0 = ed.y, e1 = ed.z;
    float v0 = x0[src*4 + c];
    const float* q1 = x1 + src*12 + c*3;
    const float* q2 = x2 + src*20 + c*5;
    a0[0] = fmaf(e0, v0, a0[0]);
    a0[1] = fmaf(e1, v0, a0[1]);
    #pragma unroll
    for(int m=0;m<3;m++){ float v=q1[m]; a1[0][m]=fmaf(e0,v,a1[0][m]); a1[1][m]=fmaf(e1,v,a1[1][m]); }
    #pragma unroll
    for(int m=0;m<5;m++){ float v=q2[m]; a2[0][m]=fmaf(e0,v,a2[0][m]); a2[1][m]=fmaf(e1,v,a2[1][m]); }
  }
  #pragma unroll
  for(int ech=0;ech<2;ech++){
    int ch = ech*4 + c;
    y[ch*NN + node] = a0[ech];
    #pragma unroll
    for(int m=0;m<3;m++) y[(8  + ch*3 + m)*NN + node] = a1[ech][m];
    #pragma unroll
    for(int m=0;m<5;m++) y[(32 + ch*5 + m)*NN + node] = a2[ech][m];
  }
}

extern "C" void kernel_launch(void* const* d_in, const int* in_sizes, int n_in,
                              void* d_out, int out_size, void* d_ws, size_t ws_size,
                              hipStream_t stream)
{
  const float* x0 = (const float*)d_in[0];
  const float* x1 = (const float*)d_in[1];
  const float* x2 = (const float*)d_in[2];
  const float* ev = (const float*)d_in[3];
  const int* idx  = (const int*)d_in[13];

  WPtrs w;
  for(int l=0;l<3;l++){
    w.xx[l] = (const float*)d_in[4+l];
    w.yx[l] = (const float*)d_in[7+l];
    w.yy[l] = (const float*)d_in[10+l];
  }

  // workspace layout
  float4* edges = (float4*)d_ws;            // NE  (7.68 MB)
  int*    cnt   = (int*)(edges + NE);       // NN
  int*    offs  = cnt + NN;                 // NN+1
  int*    cur   = offs + NN + 1;            // NN
  int*    bt    = cur + NN;                 // 64
  int*    bte   = bt + 64;                  // 64
  float*  xs    = (float*)(bte + 64);       // NN*36
  float*  y     = xs + NN*36;               // NN*72
  float*  p0    = y  + NN*72;               // NN*72
  float*  p1    = p0 + NN*72;               // NN*72
  float*  p2    = p1 + NN*72;               // NN*72

  hipMemsetAsync(cnt, 0, (size_t)NN*sizeof(int), stream);

  hist_kernel<<<(NE+255)/256, 256, 0, stream>>>(idx, cnt);
  scan1_kernel<<<64, 256, 0, stream>>>(cnt, offs, bt);
  scan2_kernel<<<1, 64, 0, stream>>>(bt, bte, offs);
  scan3_kernel<<<64, 512, 0, stream>>>(offs, bte, cur);
  scatter_kernel<<<(NE+255)/256, 256, 0, stream>>>(idx, ev, cur, edges);
  xpose_kernel<<<(NN*36+255)/256, 256, 0, stream>>>(x0, x1, x2, xs);
  gather_kernel<<<(NN*4+255)/256, 256, 0, stream>>>(x0, x1, x2, edges, offs, y);

  cg_kernel<<<NGB*9, 256, 0, stream>>>(xs, y, w, p0, p1, p2);

  sum_kernel<<<(NN*72+255)/256, 256, 0, stream>>>(p0, p1, p2, (float*)d_out);
}

// Round 9
// 245.995 us; speedup vs baseline: 1.2027x; 1.2027x over previous
//
#include <hip/hip_runtime.h>
#include <stdint.h>

#define NN 30000
#define NE 480000
#define NB 469              // ceil(NN/64) node-groups

// ------------------------- compile-time Clebsch-Gordan -------------------------
constexpr double cfact(int n){ double r=1.0; for(int i=2;i<=n;i++) r*=(double)i; return r; }
constexpr double csqrt_(double x){ if(x<=0.0) return 0.0; double g = x<1.0?1.0:x; for(int i=0;i<200;i++) g = 0.5*(g + x/g); return g; }
constexpr double cg_coeff(int j1,int m1,int j2,int m2,int j,int m){
  if(m != m1+m2) return 0.0;
  int dj = j1-j2; if(dj<0) dj=-dj;
  if(j < dj || j > j1+j2) return 0.0;
  double pre = csqrt_((2*j+1)*cfact(j+j1-j2)*cfact(j-j1+j2)*cfact(j1+j2-j)/cfact(j1+j2+j+1));
  pre = pre * csqrt_(cfact(j+m)*cfact(j-m)*cfact(j1-m1)*cfact(j1+m1)*cfact(j2-m2)*cfact(j2+m2));
  double s = 0.0;
  for(int k=0;k<=j1+j2-j;k++){
    int d0=k, d1=j1+j2-j-k, d2=j1-m1-k, d3=j2+m2-k, d4=j-j2+m1+k, d5=j-j1-m2+k;
    if(d0<0||d1<0||d2<0||d3<0||d4<0||d5<0) continue;
    double term = 1.0/(cfact(d0)*cfact(d1)*cfact(d2)*cfact(d3)*cfact(d4)*cfact(d5));
    s += (k&1) ? -term : term;
  }
  return pre*s;
}

template<int L1,int L2,int LO> struct CGTab { float v[2*LO+1][2*L1+1][2*L2+1]; };

template<int L1,int L2,int LO>
constexpr CGTab<L1,L2,LO> make_cg(){
  CGTab<L1,L2,LO> t{};
  for(int m=-LO;m<=LO;m++)
    for(int p=-L1;p<=L1;p++)
      for(int q=-L2;q<=L2;q++)
        t.v[m+LO][p+L1][q+L2] = (float)cg_coeff(L1,p,L2,q,LO,m);
  return t;
}
template<int L1,int L2,int LO>
constexpr CGTab<L1,L2,LO> CG_TAB = make_cg<L1,L2,LO>();

// T[m] = sum_{p,q} C[m,p,q] av[p] bv[q]
template<int L1,int L2,int LO>
__device__ __forceinline__ void build_T(const float* av, const float* bv, float* T){
  constexpr int MA=2*L1+1, MB=2*L2+1, MO=2*LO+1;
  #pragma unroll
  for(int m=0;m<MO;m++) T[m]=0.f;
  #pragma unroll
  for(int m=0;m<MO;m++)
    #pragma unroll
    for(int p=0;p<MA;p++)
      #pragma unroll
      for(int q=0;q<MB;q++){
        const float cg = CG_TAB<L1,L2,LO>.v[m][p][q];
        if(cg!=0.0f) T[m]=fmaf(cg*av[p],bv[q],T[m]);
      }
}

// --------------- chunk helpers: A/B in LDS, row stride 64 ---------------
template<int L1,int L2,int LO,int CA,int CB>
__device__ __forceinline__ void do_chunk(const float* __restrict__ A,
                                         const float* __restrict__ B,
                                         const float* __restrict__ W, int wb,
                                         float acc[8][2*LO+1])
{
  constexpr int MA=2*L1+1, MB=2*L2+1, MO=2*LO+1;
  float bv[CB][MB];
  #pragma unroll
  for(int d=0;d<CB;d++)
    #pragma unroll
    for(int q=0;q<MB;q++) bv[d][q] = B[(d*MB+q)*64];
  #pragma unroll 1
  for(int c=0;c<CA;c++){
    float av[MA];
    #pragma unroll
    for(int p=0;p<MA;p++) av[p] = A[(c*MA+p)*64];
    #pragma unroll
    for(int d=0;d<CB;d++){
      float T[MO];
      build_T<L1,L2,LO>(av, bv[d], T);
      const float* wr = W + (wb + c*CB + d)*8;     // wave-uniform -> s_load
      #pragma unroll
      for(int o=0;o<8;o++){
        float w = wr[o];
        #pragma unroll
        for(int m=0;m<MO;m++) acc[o][m] = fmaf(w, T[m], acc[o][m]);
      }
    }
  }
}

template<int L1,int L2,int LO,int C,int SGN>
__device__ __forceinline__ void do_chunk_fold(const float* __restrict__ A1,
    const float* __restrict__ A2, const float* __restrict__ W, int wb1, int wb2,
    float acc[8][2*LO+1])
{
  constexpr int MA=2*L1+1, MB=2*L2+1, MO=2*LO+1;
  float bv[C][MB];
  #pragma unroll
  for(int d=0;d<C;d++)
    #pragma unroll
    for(int q=0;q<MB;q++) bv[d][q] = A2[(d*MB+q)*64];
  #pragma unroll 1
  for(int c=0;c<C;c++){
    float av[MA];
    #pragma unroll
    for(int p=0;p<MA;p++) av[p] = A1[(c*MA+p)*64];
    #pragma unroll
    for(int d=0;d<C;d++){
      float T[MO];
      build_T<L1,L2,LO>(av, bv[d], T);
      const float* w1 = W + (wb1 + c*C + d)*8;
      const float* w2 = W + (wb2 + d*C + c)*8;
      #pragma unroll
      for(int o=0;o<8;o++){
        float wf = (SGN>0) ? (w1[o] + w2[o]) : (w1[o] - w2[o]);
        #pragma unroll
        for(int m=0;m<MO;m++) acc[o][m] = fmaf(wf, T[m], acc[o][m]);
      }
    }
  }
}

template<int L,int LO,int C,int SGN>
__device__ __forceinline__ void do_chunk_tri(const float* __restrict__ Al,
    const float* __restrict__ W, int wb, float acc[8][2*LO+1])
{
  constexpr int M=2*L+1, MO=2*LO+1;
  float bv[C][M];
  #pragma unroll
  for(int d=0;d<C;d++)
    #pragma unroll
    for(int q=0;q<M;q++) bv[d][q] = Al[(d*M+q)*64];
  #pragma unroll 1
  for(int c=0;c<C-1;c++){
    float av[M];
    #pragma unroll
    for(int p=0;p<M;p++) av[p] = Al[(c*M+p)*64];
    #pragma unroll
    for(int d=0;d<C;d++){
      if(d > c){
        float T[MO];
        build_T<L,L,LO>(av, bv[d], T);
        const float* w1 = W + (wb + c*C + d)*8;
        const float* w2 = W + (wb + d*C + c)*8;
        #pragma unroll
        for(int o=0;o<8;o++){
          float wf = (SGN>0) ? (w1[o] + w2[o]) : (w1[o] - w2[o]);
          #pragma unroll
          for(int m=0;m<MO;m++) acc[o][m] = fmaf(wf, T[m], acc[o][m]);
        }
      }
    }
  }
}

template<int L,int LO,int C>
__device__ __forceinline__ void do_chunk_diagO(const float* __restrict__ Al,
    const float* __restrict__ W, int wb, float acc[8][2*LO+1])
{
  constexpr int M=2*L+1, MO=2*LO+1;
  #pragma unroll 1
  for(int c=0;c<C;c++){
    float av[M];
    #pragma unroll
    for(int p=0;p<M;p++) av[p] = Al[(c*M+p)*64];
    float T[MO];
    build_T<L,L,LO>(av, av, T);
    const float* wr = W + (wb + c*C + c)*8;
    #pragma unroll
    for(int o=0;o<8;o++){
      float w = wr[o];
      #pragma unroll
      for(int m=0;m<MO;m++) acc[o][m] = fmaf(w, T[m], acc[o][m]);
    }
  }
}

template<int LO,int CA,int CB>
__device__ __forceinline__ void run_chunks(
    const float* a0,const float* a1,const float* a2,
    const float* b0,const float* b1,const float* b2,
    const float* __restrict__ W, float acc[8][2*LO+1])
{
  constexpr int S = CA*CB;
  if constexpr (LO==0){
    do_chunk<0,0,0,CA,CB>(a0,b0,W,0*S,acc);
    do_chunk<1,1,0,CA,CB>(a1,b1,W,1*S,acc);
    do_chunk<2,2,0,CA,CB>(a2,b2,W,2*S,acc);
  } else if constexpr (LO==1){
    do_chunk<0,1,1,CA,CB>(a0,b1,W,0*S,acc);
    do_chunk<1,0,1,CA,CB>(a1,b0,W,1*S,acc);
    do_chunk<1,1,1,CA,CB>(a1,b1,W,2*S,acc);
    do_chunk<1,2,1,CA,CB>(a1,b2,W,3*S,acc);
    do_chunk<2,1,1,CA,CB>(a2,b1,W,4*S,acc);
    do_chunk<2,2,1,CA,CB>(a2,b2,W,5*S,acc);
  } else {
    do_chunk<0,2,2,CA,CB>(a0,b2,W,0*S,acc);
    do_chunk<1,1,2,CA,CB>(a1,b1,W,1*S,acc);
    do_chunk<1,2,2,CA,CB>(a1,b2,W,2*S,acc);
    do_chunk<2,0,2,CA,CB>(a2,b0,W,3*S,acc);
    do_chunk<2,1,2,CA,CB>(a2,b1,W,4*S,acc);
    do_chunk<2,2,2,CA,CB>(a2,b2,W,5*S,acc);
  }
}

template<int LO,int C>
__device__ __forceinline__ void run_chunks_sym(
    const float* a0,const float* a1,const float* a2,
    const float* __restrict__ W, float acc[8][2*LO+1])
{
  constexpr int S = C*C;
  if constexpr (LO==0){
    do_chunk_tri<0,0,C,+1>(a0,W,0*S,acc);  do_chunk_diagO<0,0,C>(a0,W,0*S,acc);
    do_chunk_tri<1,0,C,+1>(a1,W,1*S,acc);  do_chunk_diagO<1,0,C>(a1,W,1*S,acc);
    do_chunk_tri<2,0,C,+1>(a2,W,2*S,acc);  do_chunk_diagO<2,0,C>(a2,W,2*S,acc);
  } else if constexpr (LO==1){
    do_chunk_fold<0,1,1,C,+1>(a0,a1,W,0*S,1*S,acc);
    do_chunk_tri <1,1,C,-1>(a1,W,2*S,acc);
    do_chunk_fold<1,2,1,C,+1>(a1,a2,W,3*S,4*S,acc);
    do_chunk_tri <2,1,C,-1>(a2,W,5*S,acc);
  } else {
    do_chunk_fold<0,2,2,C,+1>(a0,a2,W,0*S,3*S,acc);
    do_chunk_tri <1,2,C,+1>(a1,W,1*S,acc);  do_chunk_diagO<1,2,C>(a1,W,1*S,acc);
    do_chunk_fold<1,2,2,C,-1>(a1,a2,W,2*S,4*S,acc);
    do_chunk_tri <2,2,C,+1>(a2,W,5*S,acc);  do_chunk_diagO<2,2,C>(a2,W,5*S,acc);
  }
}

// One lane = one node for one (PROD,LO); inputs in LDS (stride 64), output atomic-added
// into so (stride 65, conflict-free).
template<int PROD,int LO>
__device__ __forceinline__ void do_item_lds(int lane,
    const float* __restrict__ sx, const float* __restrict__ sy,
    const float* __restrict__ W, float* __restrict__ so)
{
  const float *y0 = sy + lane, *y1 = sy + 8*64 + lane, *y2 = sy + 32*64 + lane;
  const float *x0 = sx + lane, *x1 = sx + 4*64 + lane, *x2 = sx + 16*64 + lane;
  constexpr int MO = 2*LO+1;

  float acc[8][MO];
  #pragma unroll
  for(int o=0;o<8;o++)
    #pragma unroll
    for(int m=0;m<MO;m++) acc[o][m]=0.f;

  if constexpr (PROD==0)      run_chunks_sym<LO,8>(y0,y1,y2,W,acc);
  else if constexpr (PROD==2) run_chunks_sym<LO,4>(x0,x1,x2,W,acc);
  else                        run_chunks<LO,8,4>(y0,y1,y2,x0,x1,x2,W,acc);

  constexpr int OB = (LO==0)?0:((LO==1)?8:32);
  #pragma unroll
  for(int o=0;o<8;o++)
    #pragma unroll
    for(int m=0;m<MO;m++)
      atomicAdd(&so[(OB + o*MO + m)*65 + lane], acc[o][m]);
}

struct WPtrs {
  const float* xx[3];
  const float* yx[3];
  const float* yy[3];
};

// ---------------- fused kernel: gather(in-LDS) + all 9 CG items + out write ----------------
// Block = 64 nodes. Phase 1: stage x (LDS transpose) + zero so + gather y into LDS.
// Phase 2: 4 balanced wave-slots compute the 9 items from LDS. Phase 3: coalesced AoS out.
__global__ __launch_bounds__(256,2) void fused_kernel(
    const float* __restrict__ x0, const float* __restrict__ x1, const float* __restrict__ x2,
    const float4* __restrict__ edges, const int* __restrict__ offs,
    WPtrs w, float* __restrict__ out)
{
  __shared__ float sy[72*64];      // y rows (stride 64)
  __shared__ float sx[36*64];      // x rows (stride 64)
  __shared__ float so[72*65];      // out rows (stride 65: conflict-free)

  const int tid = threadIdx.x;
  const int node0 = blockIdx.x*64;

  // ---- zero so ----
  #pragma unroll
  for(int i=tid;i<72*65;i+=256) so[i]=0.f;

  // ---- stage x: AoS global -> SoA LDS (transpose) ----
  for(int i=tid;i<64*4;i+=256){                  // x0: rows 0..3
    int gi = node0*4 + i;
    sx[(i&3)*64 + (i>>2)] = (gi < NN*4) ? x0[gi] : 0.f;
  }
  for(int i=tid;i<64*12;i+=256){                 // x1: rows 4..15
    int gi = node0*12 + i;
    sx[(4 + i%12)*64 + i/12] = (gi < NN*12) ? x1[gi] : 0.f;
  }
  for(int i=tid;i<64*20;i+=256){                 // x2: rows 16..35
    int gi = node0*20 + i;
    sx[(16 + i%20)*64 + i/20] = (gi < NN*20) ? x2[gi] : 0.f;
  }

  // ---- gather: thread (ln, c) accumulates its node's in-edges, writes y LDS rows ----
  {
    int ln = tid >> 2, c = tid & 3;
    int gn = node0 + ln;
    float a0[2]={0.f,0.f};
    float a1[2][3]={}, a2[2][5]={};
    if(gn < NN){
      int k0 = offs[gn], k1 = offs[gn+1];
      for(int k=k0;k<k1;k++){
        float4 ed = edges[k];
        int src = __float_as_int(ed.x);
        float e0 = ed.y, e1 = ed.z;
        float v0 = x0[src*4 + c];
        const float* q1 = x1 + src*12 + c*3;
        const float* q2 = x2 + src*20 + c*5;
        a0[0] = fmaf(e0, v0, a0[0]);
        a0[1] = fmaf(e1, v0, a0[1]);
        #pragma unroll
        for(int m=0;m<3;m++){ float v=q1[m]; a1[0][m]=fmaf(e0,v,a1[0][m]); a1[1][m]=fmaf(e1,v,a1[1][m]); }
        #pragma unroll
        for(int m=0;m<5;m++){ float v=q2[m]; a2[0][m]=fmaf(e0,v,a2[0][m]); a2[1][m]=fmaf(e1,v,a2[1][m]); }
      }
    }
    #pragma unroll
    for(int ech=0;ech<2;ech++){
      int ch = ech*4 + c;
      sy[ch*64 + ln] = a0[ech];
      #pragma unroll
      for(int m=0;m<3;m++) sy[(8  + ch*3 + m)*64 + ln] = a1[ech][m];
      #pragma unroll
      for(int m=0;m<5;m++) sy[(32 + ch*5 + m)*64 + ln] = a2[ech][m];
    }
  }
  __syncthreads();

  // ---- compute: 4 wave-slots, balanced (~12-13k lane-ops each) ----
  {
    int lane = tid & 63, slot = tid >> 6;
    switch(slot){
      case 0: do_item_lds<1,2>(lane,sx,sy,w.yx[2],so); break;
      case 1: do_item_lds<0,2>(lane,sx,sy,w.yy[2],so); break;
      case 2: do_item_lds<0,1>(lane,sx,sy,w.yy[1],so);
              do_item_lds<2,2>(lane,sx,sy,w.xx[2],so);
              do_item_lds<0,0>(lane,sx,sy,w.yy[0],so); break;
      case 3: do_item_lds<1,1>(lane,sx,sy,w.yx[1],so);
              do_item_lds<2,1>(lane,sx,sy,w.xx[1],so);
              do_item_lds<1,0>(lane,sx,sy,w.yx[0],so);
              do_item_lds<2,0>(lane,sx,sy,w.xx[0],so); break;
    }
  }
  __syncthreads();

  // ---- write out (AoS reference layout), coalesced ----
  for(int i=tid;i<64*8;i+=256){                  // l0
    int n=i>>3, o=i&7;
    if(node0+n < NN) out[(node0+n)*8 + o] = so[o*65 + n];
  }
  for(int i=tid;i<64*24;i+=256){                 // l1
    int n=i/24, r=i-n*24;
    if(node0+n < NN) out[NN*8 + (node0+n)*24 + r] = so[(8+r)*65 + n];
  }
  for(int i=tid;i<64*40;i+=256){                 // l2
    int n=i/40, r=i-n*40;
    if(node0+n < NN) out[NN*32 + (node0+n)*40 + r] = so[(32+r)*65 + n];
  }
}

// ------------------------- CSR build -------------------------
__global__ __launch_bounds__(256) void hist_kernel(const int* __restrict__ idx, int* __restrict__ cnt)
{
  int e = blockIdx.x*256 + threadIdx.x;
  if(e >= NE) return;
  atomicAdd(&cnt[idx[NE + e]], 1);
}

__global__ __launch_bounds__(256) void scan1_kernel(const int* __restrict__ cnt,
    int* __restrict__ offs, int* __restrict__ bt)
{
  __shared__ int wsum[4], wexc[4];
  int b = blockIdx.x, tid = threadIdx.x;
  int lane = tid & 63, wid = tid >> 6;
  int i0 = b*512 + tid*2;
  int v0 = (i0   < NN) ? cnt[i0]   : 0;
  int v1 = (i0+1 < NN) ? cnt[i0+1] : 0;
  int v = v0+v1, s = v;
  #pragma unroll
  for(int o=1;o<64;o<<=1){ int t=__shfl_up(s,o,64); if(lane>=o) s+=t; }
  if(lane==63) wsum[wid]=s;
  __syncthreads();
  if(tid<4){
    int wv=wsum[tid], x=wv;
    #pragma unroll
    for(int o=1;o<4;o<<=1){ int t=__shfl_up(x,o,4); if(tid>=o) x+=t; }
    wexc[tid]=x-wv;
    if(tid==3) bt[b]=x;
  }
  __syncthreads();
  int excl = s - v + wexc[wid];
  if(i0   < NN) offs[i0]   = excl;
  if(i0+1 < NN) offs[i0+1] = excl + v0;
}

__global__ __launch_bounds__(64) void scan2_kernel(int* __restrict__ bt,
    int* __restrict__ bte, int* __restrict__ offs)
{
  int tid = threadIdx.x;
  int v = bt[tid], s = v;
  #pragma unroll
  for(int o=1;o<64;o<<=1){ int t=__shfl_up(s,o,64); if(tid>=o) s+=t; }
  bte[tid] = s - v;
  if(tid==63) offs[NN] = s;
}

__global__ __launch_bounds__(512) void scan3_kernel(int* __restrict__ offs,
    const int* __restrict__ bte, int* __restrict__ cur)
{
  int i = blockIdx.x*512 + threadIdx.x;
  if(i >= NN) return;
  int o = offs[i] + bte[blockIdx.x];
  offs[i] = o;
  cur[i]  = o;
}

__global__ __launch_bounds__(256) void scatter_kernel(const int* __restrict__ idx,
    const float* __restrict__ ev, int* __restrict__ cur, float4* __restrict__ edges)
{
  int e = blockIdx.x*256 + threadIdx.x;
  if(e >= NE) return;
  int dst = idx[NE + e];
  int pos = atomicAdd(&cur[dst], 1);
  float4 r;
  r.x = __int_as_float(idx[e]);
  r.y = ev[2*e];
  r.z = ev[2*e+1];
  r.w = 0.f;
  edges[pos] = r;
}

extern "C" void kernel_launch(void* const* d_in, const int* in_sizes, int n_in,
                              void* d_out, int out_size, void* d_ws, size_t ws_size,
                              hipStream_t stream)
{
  const float* x0 = (const float*)d_in[0];
  const float* x1 = (const float*)d_in[1];
  const float* x2 = (const float*)d_in[2];
  const float* ev = (const float*)d_in[3];
  const int* idx  = (const int*)d_in[13];

  WPtrs w;
  for(int l=0;l<3;l++){
    w.xx[l] = (const float*)d_in[4+l];
    w.yx[l] = (const float*)d_in[7+l];
    w.yy[l] = (const float*)d_in[10+l];
  }

  // workspace layout
  float4* edges = (float4*)d_ws;            // NE  (7.68 MB)
  int*    cnt   = (int*)(edges + NE);       // NN
  int*    offs  = cnt + NN;                 // NN+1
  int*    cur   = offs + NN + 1;            // NN
  int*    bt    = cur + NN;                 // 64
  int*    bte   = bt + 64;                  // 64

  hipMemsetAsync(cnt, 0, (size_t)NN*sizeof(int), stream);

  hist_kernel<<<(NE+255)/256, 256, 0, stream>>>(idx, cnt);
  scan1_kernel<<<64, 256, 0, stream>>>(cnt, offs, bt);
  scan2_kernel<<<1, 64, 0, stream>>>(bt, bte, offs);
  scan3_kernel<<<64, 512, 0, stream>>>(offs, bte, cur);
  scatter_kernel<<<(NE+255)/256, 256, 0, stream>>>(idx, ev, cur, edges);

  fused_kernel<<<NB, 256, 0, stream>>>(x0, x1, x2, edges, offs, w, (float*)d_out);
}